// Round 4
// baseline (6132.098 us; speedup 1.0000x reference)
//
#include <hip/hip_runtime.h>
#include <hip/hip_bf16.h>

using short8  = __attribute__((ext_vector_type(8))) short;
using floatx4 = __attribute__((ext_vector_type(4))) float;
using u16     = unsigned short;

#define NBATCH   4
#define SEQ      4096
#define DMODEL   1024
#define BR       32
#define BC       64
#define NTHREADS 512
#define SCALE    0.03125f   // 1/sqrt(1024)

__device__ __forceinline__ u16 f2bf(float x) {
  union { __hip_bfloat16 h; u16 u; } cv;
  cv.h = __float2bfloat16(x);
  return cv.u;
}

__global__ __launch_bounds__(NTHREADS, 2)
void fa_fwd(const float* __restrict__ Qg,
            const float* __restrict__ Kg,
            const float* __restrict__ Vg,
            float* __restrict__ Og) {
  // Row pads keep 8B alignment for ushort4 stores / 16B for short8 reads,
  // and give a bank shift per row (2-way LDS aliasing = free on CDNA4).
  __shared__ __align__(16) u16   sQ[32][264];   // 32x256 bf16 Q d-chunk
  __shared__ __align__(16) u16   sK[64][264];   // 64x256 bf16 K d-chunk
  __shared__ __align__(16) float sS[32][66];    // fp32 score tile (32x64)
  __shared__ __align__(16) u16   sP[32][72];    // bf16 softmax weights
  __shared__ float sM[32], sL[32], sAl[32];     // online-softmax state

  const int tid   = threadIdx.x;
  const int w     = tid >> 6;       // wave 0..7
  const int lane  = tid & 63;
  const int quad  = lane >> 4;
  const int l15   = lane & 15;
  const int batch = blockIdx.y;
  const int q0    = blockIdx.x * BR;

  const size_t qbase  = (size_t)(batch * SEQ + q0) * DMODEL;
  const size_t kvbase = (size_t)batch * SEQ * DMODEL;

  if (tid < 32) { sM[tid] = -1e30f; sL[tid] = 0.0f; }

  // O accumulator: wave w owns rows 0..31, col tiles t = 8*ci + w (16 cols each)
  floatx4 acc[2][8];
  #pragma unroll
  for (int rt = 0; rt < 2; rt++)
    #pragma unroll
    for (int ci = 0; ci < 8; ci++)
      acc[rt][ci] = (floatx4)0.0f;

  const int wr = w >> 2, wc = w & 3;   // phase-A tile: rows 16*wr, cols 16*wc

  for (int kt = 0; kt < SEQ / BC; kt++) {
    // ================= Phase A: S = Q K^T (32x64), k over D=1024 =================
    floatx4 sacc = (floatx4)0.0f;
    for (int dc = 0; dc < 4; dc++) {
      __syncthreads();   // protect previous chunk's fragment reads
      #pragma unroll
      for (int i = 0; i < 4; i++) {          // Q chunk: 32x256 f32 = 2048 float4
        const int e   = tid + i * NTHREADS;
        const int row = e >> 6;
        const int c4  = (e & 63) << 2;
        float4 v = *(const float4*)&Qg[qbase + (size_t)row * DMODEL + dc * 256 + c4];
        ushort4 pk = { f2bf(v.x), f2bf(v.y), f2bf(v.z), f2bf(v.w) };
        *(ushort4*)&sQ[row][c4] = pk;
      }
      #pragma unroll
      for (int i = 0; i < 8; i++) {          // K chunk: 64x256 f32 = 4096 float4
        const int e   = tid + i * NTHREADS;
        const int row = e >> 6;
        const int c4  = (e & 63) << 2;
        float4 v = *(const float4*)&Kg[kvbase + (size_t)(kt * BC + row) * DMODEL + dc * 256 + c4];
        ushort4 pk = { f2bf(v.x), f2bf(v.y), f2bf(v.z), f2bf(v.w) };
        *(ushort4*)&sK[row][c4] = pk;
      }
      __syncthreads();
      #pragma unroll
      for (int ks = 0; ks < 8; ks++) {
        // A: lane holds Q[m=l15][k=quad*8+j]; B: lane holds K[n=l15][k=quad*8+j]
        short8 av = *(const short8*)&sQ[wr * 16 + l15][ks * 32 + quad * 8];
        short8 bv = *(const short8*)&sK[wc * 16 + l15][ks * 32 + quad * 8];
        sacc = __builtin_amdgcn_mfma_f32_16x16x32_bf16(av, bv, sacc, 0, 0, 0);
      }
    }
    // C/D layout: col = l15, row = quad*4 + r
    #pragma unroll
    for (int r = 0; r < 4; r++)
      sS[wr * 16 + quad * 4 + r][wc * 16 + l15] = sacc[r];
    __syncthreads();

    // ================= Phase B: online softmax (16 threads per row) =================
    {
      const int row = tid >> 4;
      const int c0  = tid & 15;
      float v0 = sS[row][c0     ] * SCALE;
      float v1 = sS[row][c0 + 16] * SCALE;
      float v2 = sS[row][c0 + 32] * SCALE;
      float v3 = sS[row][c0 + 48] * SCALE;
      float mx = fmaxf(fmaxf(v0, v1), fmaxf(v2, v3));
      #pragma unroll
      for (int off = 8; off >= 1; off >>= 1)
        mx = fmaxf(mx, __shfl_xor(mx, off, 16));
      const float m_old = sM[row];
      const float m_new = fmaxf(m_old, mx);
      const float p0 = __expf(v0 - m_new);
      const float p1 = __expf(v1 - m_new);
      const float p2 = __expf(v2 - m_new);
      const float p3 = __expf(v3 - m_new);
      sP[row][c0     ] = f2bf(p0);
      sP[row][c0 + 16] = f2bf(p1);
      sP[row][c0 + 32] = f2bf(p2);
      sP[row][c0 + 48] = f2bf(p3);
      float sum = p0 + p1 + p2 + p3;
      #pragma unroll
      for (int off = 8; off >= 1; off >>= 1)
        sum += __shfl_xor(sum, off, 16);
      if (c0 == 0) {
        const float al = __expf(m_old - m_new);   // exp(-1e30 - m) == 0 on first tile
        sAl[row] = al;
        sM[row]  = m_new;
        sL[row]  = sL[row] * al + sum;
      }
    }
    __syncthreads();

    // ================= rescale O by alpha =================
    float alv[2][4];
    #pragma unroll
    for (int rt = 0; rt < 2; rt++)
      #pragma unroll
      for (int r = 0; r < 4; r++)
        alv[rt][r] = sAl[rt * 16 + quad * 4 + r];
    #pragma unroll
    for (int rt = 0; rt < 2; rt++)
      #pragma unroll
      for (int ci = 0; ci < 8; ci++)
        #pragma unroll
        for (int r = 0; r < 4; r++)
          acc[rt][ci][r] *= alv[rt][r];

    // ================= Phase C: O += P V (V B-frags direct from global) =========
    #pragma unroll
    for (int ks = 0; ks < 2; ks++) {
      short8 a0 = *(const short8*)&sP[l15     ][ks * 32 + quad * 8];
      short8 a1 = *(const short8*)&sP[16 + l15][ks * 32 + quad * 8];
      #pragma unroll 4
      for (int ci = 0; ci < 8; ci++) {
        const int col = ((ci << 3) + w) * 16 + l15;      // d column (n = l15)
        const float* vp = Vg + kvbase +
                          (size_t)(kt * BC + ks * 32 + quad * 8) * DMODEL + col;
        short8 bv;    // B: lane holds V[k=quad*8+j][n=col]
        #pragma unroll
        for (int j = 0; j < 8; j++)
          bv[j] = (short)f2bf(vp[(size_t)j * DMODEL]);
        acc[0][ci] = __builtin_amdgcn_mfma_f32_16x16x32_bf16(a0, bv, acc[0][ci], 0, 0, 0);
        acc[1][ci] = __builtin_amdgcn_mfma_f32_16x16x32_bf16(a1, bv, acc[1][ci], 0, 0, 0);
      }
    }
  }

  // ================= epilogue: O /= l, store FLOAT32 (reference output dtype) ==
  float linv[2][4];
  #pragma unroll
  for (int rt = 0; rt < 2; rt++)
    #pragma unroll
    for (int r = 0; r < 4; r++)
      linv[rt][r] = 1.0f / sL[rt * 16 + quad * 4 + r];
  #pragma unroll
  for (int rt = 0; rt < 2; rt++)
    #pragma unroll
    for (int ci = 0; ci < 8; ci++) {
      const int col = ((ci << 3) + w) * 16 + l15;
      #pragma unroll
      for (int r = 0; r < 4; r++) {
        const int row = q0 + rt * 16 + quad * 4 + r;
        Og[(size_t)(batch * SEQ + row) * DMODEL + col] = acc[rt][ci][r] * linv[rt][r];
      }
    }
}

extern "C" void kernel_launch(void* const* d_in, const int* in_sizes, int n_in,
                              void* d_out, int out_size, void* d_ws, size_t ws_size,
                              hipStream_t stream) {
  // Harness contract: inputs in setup_inputs() dict order (query, key, value),
  // f32; output dtype = reference output dtype = float32.
  const float* Q = (const float*)d_in[0];
  const float* K = (const float*)d_in[1];
  const float* V = (const float*)d_in[2];
  float* O = (float*)d_out;
  dim3 grid(SEQ / BR, NBATCH);
  fa_fwd<<<grid, NTHREADS, 0, stream>>>(Q, K, V, O);
}